// Round 15
// baseline (202.991 us; speedup 1.0000x reference)
//
#include <hip/hip_runtime.h>
#include <math.h>

#define W128  128
#define NNODE 1024
#define NREL  12
#define TS    72        // bf16 LDS tile stride (144B rows)

// ws layout (float offsets)
#define OFF_ARG1  0         // 128x1024 f32
#define OFF_ARG2  131072    // 128x1024 f32
#define OFF_ARG2B 262144    // 128x1024 bf16 (65536 floats)
#define OFF_PART  327680    // partF 16x1024x128 bf16, then partB same
#define OFF_CNT   2424832   // 16 x u32 group counters

typedef short bf16x8 __attribute__((ext_vector_type(8)));
typedef float f32x4  __attribute__((ext_vector_type(4)));

__device__ __forceinline__ short bf16t(float x) {
    return (short)(__float_as_uint(x) >> 16);
}
__device__ __forceinline__ float bf16f(short s) {
    return __uint_as_float((unsigned)(unsigned short)s << 16);
}
__device__ __forceinline__ unsigned pk2(float lo, float hi) {
    return (__float_as_uint(hi) & 0xFFFF0000u) | (__float_as_uint(lo) >> 16);
}

// ---------------- args (+ in-block column softmaxes) ----------------
// grid 256: block = 32 n x 16 w tile, 512 threads. Also zeroes group counters.
__global__ __launch_bounds__(512) void k_args3(const float* __restrict__ inputs,
                                               const float* __restrict__ a1w,
                                               const float* __restrict__ a2w,
                                               float* __restrict__ ws,
                                               short* __restrict__ x2b,
                                               unsigned* __restrict__ cnt) {
    __shared__ __align__(16) char smem[33280];
    float* lin = (float*)smem;               // [128][33]
    float* sm1 = (float*)(smem + 16896);     // [16][128]
    float* sm2 = sm1 + 16 * W128;            // [16][128]
    int t = threadIdx.x;
    int bid = blockIdx.x;
    if (bid == 0 && t < 16) cnt[t] = 0;      // fresh counters every call
    int n0 = (bid & 31) * 32;
    int w0 = (bid >> 5) * 16;
    // stage inputs[128][32] once
#pragma unroll
    for (int u = 0; u < 8; ++u) {
        int idx = t + u * 512;
        int j = idx >> 5, nn = idx & 31;
        lin[j * 33 + nn] = inputs[j * NNODE + n0 + nn];
    }
    // 32 column softmaxes (16 w x {a1w,a2w}), 16 lanes per column
    {
        int c = t >> 4, i = t & 15;
        const float* src = (c < 16) ? a1w : a2w;
        float* dst = (c < 16) ? sm1 : sm2;
        int w_loc = c & 15;
        int wcol = w0 + w_loc;
        float v[8]; float mx = -1e30f;
#pragma unroll
        for (int k = 0; k < 8; ++k) {
            v[k] = src[(i * 8 + k) * W128 + wcol];
            mx = fmaxf(mx, v[k]);
        }
#pragma unroll
        for (int off = 8; off; off >>= 1) mx = fmaxf(mx, __shfl_xor(mx, off));
        float s = 0.f;
#pragma unroll
        for (int k = 0; k < 8; ++k) { v[k] = expf(v[k] - mx); s += v[k]; }
#pragma unroll
        for (int off = 8; off; off >>= 1) s += __shfl_xor(s, off);
        float inv = 1.0f / s;
#pragma unroll
        for (int k = 0; k < 8; ++k) dst[w_loc * W128 + i * 8 + k] = v[k] * inv;
    }
    __syncthreads();
    // each thread: one (n, w) pair
    int nn = t & 31, w_loc = t >> 5;
    int n = n0 + nn, w = w0 + w_loc;
    const float* s1 = sm1 + w_loc * W128;
    const float* s2 = sm2 + w_loc * W128;
    float a1 = 0.f, a2 = 0.f;
#pragma unroll 4
    for (int j = 0; j < W128; ++j) {
        float in = lin[j * 33 + nn];
        a1 = fmaf(s1[j], in, a1);
        a2 = fmaf(s2[j], in, a2);
    }
    ws[OFF_ARG1 + w * NNODE + n] = a1;
    ws[OFF_ARG2 + w * NNODE + n] = a2;
    x2b[w * NNODE + n] = bf16t(a2);
}

// ---------------- chain + last-block reduce (2-dispatch structure) ----------
// Chain body identical to verified k_chain4. After partials: device-scope
// counter; the block whose increment completes a 64-node group reduces it
// (fixed-order sum -> bitwise deterministic regardless of which block runs it).
__global__ __launch_bounds__(512) void k_chainred(const float* __restrict__ db,
                                                  const float* __restrict__ chw,
                                                  const float* __restrict__ opww,
                                                  const float* __restrict__ ws,
                                                  const short* __restrict__ x2b,
                                                  short* __restrict__ partF,
                                                  short* __restrict__ partB,
                                                  unsigned* __restrict__ cnt,
                                                  float* __restrict__ out) {
    __shared__ __align__(16) short Tf[64 * TS];  // T[a][b]
    __shared__ __align__(16) short Tt[64 * TS];  // T^T[c][a]
    __shared__ float wfs[W128 * NREL];
    __shared__ float wbs[W128 * NREL];
    __shared__ float chs[64 * 129];              // reduce transpose buffer
    __shared__ float opws[5 * W128];             // normalized op weights
    __shared__ unsigned uflags[2];

    int tid = threadIdx.x;
    int gx = blockIdx.x, gy = blockIdx.y;
    int B0 = gx * 64;   // fwd out-node range / bwd contraction range
    int A0 = gy * 64;   // bwd out-node range / fwd contraction range

    // issue first tile's global loads ASAP (overlap with softmax below)
    int a0 = 2 * (tid >> 4), c0 = 4 * (tid & 15);
    const float* gbase = db + (size_t)(A0 + a0) * NNODE + B0 + c0;
    const size_t rstep = (size_t)NNODE * NNODE;
    float4 g0 = *(const float4*)(gbase);
    float4 g1 = *(const float4*)(gbase + NNODE);

    // in-block chain-weight softmax
    if (tid < 128) {
        float u[24]; float mx = -1e30f;
        for (int k = 0; k < 24; ++k) { u[k] = chw[tid * 24 + k]; mx = fmaxf(mx, u[k]); }
        float s = 0.f;
        for (int k = 0; k < 24; ++k) { u[k] = expf(u[k] - mx); s += u[k]; }
        float inv = 1.0f / s;
        for (int k = 0; k < 12; ++k) wfs[tid * NREL + k] = u[k] * inv;
        for (int k = 0; k < 12; ++k) wbs[tid * NREL + k] = u[12 + k] * inv;
    }

    int l   = tid & 63, wid = tid >> 6;
    int wm  = wid >> 2;          // 0..1 : node-half (m)
    int wn  = wid & 3;           // 0..3 : w-quarter (n)
    int l16 = l & 15, lq = l >> 4;

    // loop-invariant B-frags from x2b
    bf16x8 bfF[2][2], bfB[2][2];
#pragma unroll
    for (int ni = 0; ni < 2; ++ni)
#pragma unroll
        for (int ks = 0; ks < 2; ++ks) {
            int w = wn * 32 + ni * 16 + l16;
            bfF[ni][ks] = *(const bf16x8*)&x2b[w * NNODE + A0 + ks * 32 + lq * 8];
            bfB[ni][ks] = *(const bf16x8*)&x2b[w * NNODE + B0 + ks * 32 + lq * 8];
        }

    f32x4 accF[2][2], accB[2][2];
#pragma unroll
    for (int mi = 0; mi < 2; ++mi)
#pragma unroll
        for (int ni = 0; ni < 2; ++ni) {
            accF[mi][ni] = (f32x4){0.f, 0.f, 0.f, 0.f};
            accB[mi][ni] = (f32x4){0.f, 0.f, 0.f, 0.f};
        }

#pragma unroll 2
    for (int r = 0; r < NREL; ++r) {
        // stage packed bf16 tiles (pack once; consumers read b128 only)
        uint2 p0 = {pk2(g0.x, g0.y), pk2(g0.z, g0.w)};
        uint2 p1 = {pk2(g1.x, g1.y), pk2(g1.z, g1.w)};
        *(uint2*)&Tf[a0 * TS + c0]       = p0;
        *(uint2*)&Tf[(a0 + 1) * TS + c0] = p1;
        *(unsigned*)&Tt[(c0 + 0) * TS + a0] = pk2(g0.x, g1.x);
        *(unsigned*)&Tt[(c0 + 1) * TS + a0] = pk2(g0.y, g1.y);
        *(unsigned*)&Tt[(c0 + 2) * TS + a0] = pk2(g0.z, g1.z);
        *(unsigned*)&Tt[(c0 + 3) * TS + a0] = pk2(g0.w, g1.w);
        __syncthreads();

        float4 n0v = g0, n1v = g1;
        if (r + 1 < NREL) {
            const float* g = gbase + (size_t)(r + 1) * rstep;
            n0v = *(const float4*)(g);
            n1v = *(const float4*)(g + NNODE);
        }

        f32x4 tF[2][2], tB[2][2];
#pragma unroll
        for (int mi = 0; mi < 2; ++mi)
#pragma unroll
            for (int ni = 0; ni < 2; ++ni) {
                tF[mi][ni] = (f32x4){0.f, 0.f, 0.f, 0.f};
                tB[mi][ni] = (f32x4){0.f, 0.f, 0.f, 0.f};
            }

#pragma unroll
        for (int ks = 0; ks < 2; ++ks) {
            bf16x8 AF[2], AB[2];
#pragma unroll
            for (int mi = 0; mi < 2; ++mi) {
                int row = wm * 32 + mi * 16 + l16;
                int off = ks * 32 + lq * 8;
                AF[mi] = *(const bf16x8*)&Tt[row * TS + off];
                AB[mi] = *(const bf16x8*)&Tf[row * TS + off];
            }
#pragma unroll
            for (int mi = 0; mi < 2; ++mi)
#pragma unroll
                for (int ni = 0; ni < 2; ++ni) {
                    tF[mi][ni] = __builtin_amdgcn_mfma_f32_16x16x32_bf16(
                        AF[mi], bfF[ni][ks], tF[mi][ni], 0, 0, 0);
                    tB[mi][ni] = __builtin_amdgcn_mfma_f32_16x16x32_bf16(
                        AB[mi], bfB[ni][ks], tB[mi][ni], 0, 0, 0);
                }
        }
        __syncthreads();

        // fold per-(w,r) chain weights (w = lane column)
#pragma unroll
        for (int ni = 0; ni < 2; ++ni) {
            int w = wn * 32 + ni * 16 + l16;
            float wfv = wfs[w * NREL + r];
            float wbv = wbs[w * NREL + r];
#pragma unroll
            for (int mi = 0; mi < 2; ++mi)
#pragma unroll
                for (int v = 0; v < 4; ++v) {
                    accF[mi][ni][v] += wfv * tF[mi][ni][v];
                    accB[mi][ni][v] += wbv * tB[mi][ni][v];
                }
        }
        g0 = n0v; g1 = n1v;
    }

    // bf16 partials, [node][w]-major
#pragma unroll
    for (int mi = 0; mi < 2; ++mi)
#pragma unroll
        for (int v = 0; v < 4; ++v) {
            int m = wm * 32 + mi * 16 + lq * 4 + v;
#pragma unroll
            for (int ni = 0; ni < 2; ++ni) {
                int w = wn * 32 + ni * 16 + l16;
                partF[(size_t)gy * (NNODE * W128) + (B0 + m) * W128 + w]
                    = bf16t(accF[mi][ni][v]);
                partB[(size_t)gx * (NNODE * W128) + (A0 + m) * W128 + w]
                    = bf16t(accB[mi][ni][v]);
            }
        }

    // ---- last-block-per-group reduce ----
    __threadfence();          // make this thread's partial stores device-visible
    __syncthreads();          // all threads' fences done
    if (tid == 0) {
        unsigned o1 = __hip_atomic_fetch_add(&cnt[gx], 1u, __ATOMIC_ACQ_REL,
                                             __HIP_MEMORY_SCOPE_AGENT);
        unsigned o2 = __hip_atomic_fetch_add(&cnt[gy], 1u, __ATOMIC_ACQ_REL,
                                             __HIP_MEMORY_SCOPE_AGENT);
        uflags[0] = (o1 == 31) ? 1u : 0u;   // group gx complete
        uflags[1] = (o2 == 31) ? 1u : 0u;   // group gy complete
    }
    __syncthreads();

#pragma unroll 1
    for (int pass = 0; pass < 2; ++pass) {
        if (!uflags[pass]) continue;
        int tgrp = pass ? gy : gx;
        int n0r = tgrp * 64;
        __threadfence();       // acquire side: see other blocks' partials
        // normalized opw softmax -> LDS
        if (tid < 128) {
            float v[5], mx = -1e30f;
#pragma unroll
            for (int k = 0; k < 5; ++k) { v[k] = opww[tid * 5 + k]; mx = fmaxf(mx, v[k]); }
            float s5 = 0.f;
#pragma unroll
            for (int k = 0; k < 5; ++k) { v[k] = expf(v[k] - mx); s5 += v[k]; }
            float inv = 1.0f / s5;
#pragma unroll
            for (int k = 0; k < 5; ++k) opws[k * W128 + tid] = v[k] * inv;
        }
        // phase A: coalesced partial reduction (lane = w)
        {
            int w = tid & 127, nq = tid >> 7;
#pragma unroll 4
            for (int j = 0; j < 16; ++j) {
                int n_loc = nq + j * 4;
                size_t base = (size_t)(n0r + n_loc) * W128 + w;
                float ch = 0.f;
#pragma unroll
                for (int s = 0; s < 16; ++s) {
                    ch += bf16f(partF[(size_t)s * (NNODE * W128) + base])
                        + bf16f(partB[(size_t)s * (NNODE * W128) + base]);
                }
                chs[n_loc * 129 + w] = ch;
            }
        }
        __syncthreads();
        // phase B: transposed epilogue (lane = n) -> coalesced arg/out IO
        {
            int n_loc = tid & 63, w8 = tid >> 6;
#pragma unroll 4
            for (int k = 0; k < 16; ++k) {
                int w = w8 + k * 8;
                float ch = chs[n_loc * 129 + w];
                float a1 = ws[OFF_ARG1 + (size_t)w * NNODE + n0r + n_loc];
                float a2 = ws[OFF_ARG2 + (size_t)w * NNODE + n0r + n_loc];
                float o0 = opws[0 * W128 + w];
                float o1 = opws[1 * W128 + w];
                float o2 = opws[2 * W128 + w];
                float o3 = opws[3 * W128 + w];
                float o4 = opws[4 * W128 + w];
                float p = a1 * a2;
                out[(size_t)w * NNODE + n0r + n_loc] =
                      o0 * a2 + o1 * p + o2 * (a1 + a2 - p)
                    + o3 * (1.0f - expf(-ch)) + o4 * (1.0f - a1);
            }
        }
        __syncthreads();   // chs reuse safety for second pass
    }
}

extern "C" void kernel_launch(void* const* d_in, const int* in_sizes, int n_in,
                              void* d_out, int out_size, void* d_ws, size_t ws_size,
                              hipStream_t stream) {
    const float* inputs = (const float*)d_in[0];
    const float* db     = (const float*)d_in[1];
    const float* a1w    = (const float*)d_in[2];
    const float* a2w    = (const float*)d_in[3];
    const float* opww   = (const float*)d_in[4];
    const float* chw    = (const float*)d_in[5];
    float* ws  = (float*)d_ws;
    float* out = (float*)d_out;
    short* x2b   = (short*)(ws + OFF_ARG2B);
    short* partF = (short*)(ws + OFF_PART);
    short* partB = partF + (size_t)16 * NNODE * W128;
    unsigned* cnt = (unsigned*)(ws + OFF_CNT);

    hipLaunchKernelGGL(k_args3, dim3(256), dim3(512), 0, stream,
                       inputs, a1w, a2w, ws, x2b, cnt);
    hipLaunchKernelGGL(k_chainred, dim3(16, 16), dim3(512), 0, stream,
                       db, chw, opww, ws, x2b, partF, partB, cnt, out);
}

// Round 17
// 48.858 us; speedup vs baseline: 4.1547x; 4.1547x over previous
//
#include <hip/hip_runtime.h>
#include <math.h>

#define W128  128
#define NNODE 1024
#define NREL  12
#define TS    72    // Tf/Tt/inT stride (shorts), 144B rows
#define XS    136   // X/smT stride (shorts), 272B rows

typedef short bf16x8 __attribute__((ext_vector_type(8)));
typedef short short4v __attribute__((ext_vector_type(4)));
typedef float f32x4  __attribute__((ext_vector_type(4)));

__device__ __forceinline__ short bf16t(float x) {
    return (short)(__float_as_uint(x) >> 16);
}
__device__ __forceinline__ float bf16f(short s) {
    return __uint_as_float((unsigned)(unsigned short)s << 16);
}
__device__ __forceinline__ unsigned pk2(float lo, float hi) {
    return (__float_as_uint(hi) & 0xFFFF0000u) | (__float_as_uint(lo) >> 16);
}

// ================= kernel A: args-via-MFMA + chain =================
// grid (16,16), 512 thr. LDS aliasing (65536 B):
//   [0,34816):      smT [128][XS] (phase A)  ->  X [128][XS] (phase B)
//   [34816,53248):  inT [128][TS] j-half (A) ->  Tf/Tt head (B)
//   [34816,65536):  Tf | Tt | wfs | wbs (phase B)
__global__ __launch_bounds__(512) void k_chainA(const float* __restrict__ db,
                                                const float* __restrict__ inputs,
                                                const float* __restrict__ a2w,
                                                const float* __restrict__ chw,
                                                short* __restrict__ partF,
                                                short* __restrict__ partB) {
    __shared__ __align__(16) char smem[65536];
    short* smT = (short*)smem;
    short* X   = (short*)smem;
    short* inT = (short*)(smem + 34816);
    short* Tf  = (short*)(smem + 34816);
    short* Tt  = (short*)(smem + 44032);
    float* wfs = (float*)(smem + 53248);
    float* wbs = (float*)(smem + 59392);

    int tid = threadIdx.x;
    int gx = blockIdx.x, gy = blockIdx.y;
    int B0 = gx * 64, A0 = gy * 64;
    int l = tid & 63, wid = tid >> 6;
    int l16 = l & 15, lq = l >> 4;

    // prefetch first db tile (in flight through the whole args phase)
    int a0 = 2 * (tid >> 4), c0 = 4 * (tid & 15);
    const float* gbase = db + (size_t)(A0 + a0) * NNODE + B0 + c0;
    const size_t rstep = (size_t)NNODE * NNODE;
    float4 g0 = *(const float4*)(gbase);
    float4 g1 = *(const float4*)(gbase + NNODE);

    // ---- smT: 128 column softmaxes of a2w -> bf16 [w][j] ----
    {
        int i = tid & 15, cb = tid >> 4;   // 16 lanes per column, 32 cols/pass
#pragma unroll
        for (int p = 0; p < 4; ++p) {
            int c = p * 32 + cb;
            float v[8]; float mx = -1e30f;
#pragma unroll
            for (int k = 0; k < 8; ++k) { v[k] = a2w[(i * 8 + k) * W128 + c]; mx = fmaxf(mx, v[k]); }
#pragma unroll
            for (int off = 8; off; off >>= 1) mx = fmaxf(mx, __shfl_xor(mx, off));
            float s = 0.f;
#pragma unroll
            for (int k = 0; k < 8; ++k) { v[k] = expf(v[k] - mx); s += v[k]; }
#pragma unroll
            for (int off = 8; off; off >>= 1) s += __shfl_xor(s, off);
            float inv = 1.0f / s;
            int4 pkv;
            pkv.x = (int)pk2(v[0] * inv, v[1] * inv);
            pkv.y = (int)pk2(v[2] * inv, v[3] * inv);
            pkv.z = (int)pk2(v[4] * inv, v[5] * inv);
            pkv.w = (int)pk2(v[6] * inv, v[7] * inv);
            *(int4*)&smT[c * XS + i * 8] = pkv;
        }
    }

    // ---- args-MFMA: X[n'][w] = sum_j inT[n'][j] * smT[w][j] ----
    // M=n'(128: 0-63 A0-range, 64-127 B0-range), N=w(128), K=j(128)
    f32x4 xacc[8];
#pragma unroll
    for (int ni = 0; ni < 8; ++ni) xacc[ni] = (f32x4){0.f, 0.f, 0.f, 0.f};

#pragma unroll
    for (int half = 0; half < 2; ++half) {
        // stage inT j-half: inputs[j][gcol] -> inT[n'][j-local] bf16 transposed
#pragma unroll
        for (int u = 0; u < 2; ++u) {
            int slot = tid + u * 512;
            int jp = slot >> 5;        // 0..31 (j-pair)
            int cg = slot & 31;        // col-group of 4
            int j = half * 64 + 2 * jp;
            int gcol = (cg < 16) ? (A0 + cg * 4) : (B0 + (cg - 16) * 4);
            float4 r0 = *(const float4*)&inputs[(size_t)j * NNODE + gcol];
            float4 r1 = *(const float4*)&inputs[(size_t)(j + 1) * NNODE + gcol];
            int nb = cg * 4;
            *(unsigned*)&inT[(nb + 0) * TS + 2 * jp] = pk2(r0.x, r1.x);
            *(unsigned*)&inT[(nb + 1) * TS + 2 * jp] = pk2(r0.y, r1.y);
            *(unsigned*)&inT[(nb + 2) * TS + 2 * jp] = pk2(r0.z, r1.z);
            *(unsigned*)&inT[(nb + 3) * TS + 2 * jp] = pk2(r0.w, r1.w);
        }
        __syncthreads();   // inT (and, first pass, smT) ready
#pragma unroll
        for (int kh = 0; kh < 2; ++kh) {
            int kk = half * 2 + kh;
            bf16x8 Af = *(const bf16x8*)&inT[(wid * 16 + l16) * TS + kh * 32 + lq * 8];
#pragma unroll
            for (int ni = 0; ni < 8; ++ni) {
                bf16x8 Bf = *(const bf16x8*)&smT[(ni * 16 + l16) * XS + kk * 32 + lq * 8];
                xacc[ni] = __builtin_amdgcn_mfma_f32_16x16x32_bf16(Af, Bf, xacc[ni], 0, 0, 0);
            }
        }
        __syncthreads();   // before restaging inT / overwriting smT with X
    }

    // write X over (dead) smT: lane holds D rows n'=wid*16+lq*4+v, col w=ni*16+l16
#pragma unroll
    for (int ni = 0; ni < 8; ++ni) {
        int w = ni * 16 + l16;
        int nb = wid * 16 + lq * 4;
        uint2 pv;
        pv.x = pk2(xacc[ni][0], xacc[ni][1]);
        pv.y = pk2(xacc[ni][2], xacc[ni][3]);
        *(uint2*)&X[w * XS + nb] = pv;
    }
    // chain-weight softmax (region disjoint from X and inT)
    if (tid < 128) {
        float u2[24]; float mx = -1e30f;
        for (int k = 0; k < 24; ++k) { u2[k] = chw[tid * 24 + k]; mx = fmaxf(mx, u2[k]); }
        float s = 0.f;
        for (int k = 0; k < 24; ++k) { u2[k] = expf(u2[k] - mx); s += u2[k]; }
        float inv = 1.0f / s;
        for (int k = 0; k < 12; ++k) wfs[tid * NREL + k] = u2[k] * inv;
        for (int k = 0; k < 12; ++k) wbs[tid * NREL + k] = u2[12 + k] * inv;
    }
    __syncthreads();       // X fully written

    // loop-invariant chain B-frags from X (X[w][0..63]=A0-range, [64..127]=B0-range)
    int wm = wid >> 2, wn = wid & 3;
    bf16x8 bfF[2][2], bfB[2][2];
#pragma unroll
    for (int ni = 0; ni < 2; ++ni)
#pragma unroll
        for (int ks = 0; ks < 2; ++ks) {
            int w = wn * 32 + ni * 16 + l16;
            bfF[ni][ks] = *(const bf16x8*)&X[w * XS + ks * 32 + lq * 8];
            bfB[ni][ks] = *(const bf16x8*)&X[w * XS + 64 + ks * 32 + lq * 8];
        }

    f32x4 accF[2][2], accB[2][2];
#pragma unroll
    for (int mi = 0; mi < 2; ++mi)
#pragma unroll
        for (int ni = 0; ni < 2; ++ni) {
            accF[mi][ni] = (f32x4){0.f, 0.f, 0.f, 0.f};
            accB[mi][ni] = (f32x4){0.f, 0.f, 0.f, 0.f};
        }

    // ---- chain r-loop (verified round-13 structure) ----
#pragma unroll 2
    for (int r = 0; r < NREL; ++r) {
        uint2 p0 = {pk2(g0.x, g0.y), pk2(g0.z, g0.w)};
        uint2 p1 = {pk2(g1.x, g1.y), pk2(g1.z, g1.w)};
        *(uint2*)&Tf[a0 * TS + c0]       = p0;
        *(uint2*)&Tf[(a0 + 1) * TS + c0] = p1;
        *(unsigned*)&Tt[(c0 + 0) * TS + a0] = pk2(g0.x, g1.x);
        *(unsigned*)&Tt[(c0 + 1) * TS + a0] = pk2(g0.y, g1.y);
        *(unsigned*)&Tt[(c0 + 2) * TS + a0] = pk2(g0.z, g1.z);
        *(unsigned*)&Tt[(c0 + 3) * TS + a0] = pk2(g0.w, g1.w);
        __syncthreads();

        float4 n0v = g0, n1v = g1;
        if (r + 1 < NREL) {
            const float* g = gbase + (size_t)(r + 1) * rstep;
            n0v = *(const float4*)(g);
            n1v = *(const float4*)(g + NNODE);
        }

        f32x4 tF[2][2], tB[2][2];
#pragma unroll
        for (int mi = 0; mi < 2; ++mi)
#pragma unroll
            for (int ni = 0; ni < 2; ++ni) {
                tF[mi][ni] = (f32x4){0.f, 0.f, 0.f, 0.f};
                tB[mi][ni] = (f32x4){0.f, 0.f, 0.f, 0.f};
            }

#pragma unroll
        for (int ks = 0; ks < 2; ++ks) {
            bf16x8 AF[2], AB[2];
#pragma unroll
            for (int mi = 0; mi < 2; ++mi) {
                int row = wm * 32 + mi * 16 + l16;
                int off = ks * 32 + lq * 8;
                AF[mi] = *(const bf16x8*)&Tt[row * TS + off];
                AB[mi] = *(const bf16x8*)&Tf[row * TS + off];
            }
#pragma unroll
            for (int mi = 0; mi < 2; ++mi)
#pragma unroll
                for (int ni = 0; ni < 2; ++ni) {
                    tF[mi][ni] = __builtin_amdgcn_mfma_f32_16x16x32_bf16(
                        AF[mi], bfF[ni][ks], tF[mi][ni], 0, 0, 0);
                    tB[mi][ni] = __builtin_amdgcn_mfma_f32_16x16x32_bf16(
                        AB[mi], bfB[ni][ks], tB[mi][ni], 0, 0, 0);
                }
        }
        __syncthreads();

#pragma unroll
        for (int ni = 0; ni < 2; ++ni) {
            int w = wn * 32 + ni * 16 + l16;
            float wfv = wfs[w * NREL + r];
            float wbv = wbs[w * NREL + r];
#pragma unroll
            for (int mi = 0; mi < 2; ++mi)
#pragma unroll
                for (int v = 0; v < 4; ++v) {
                    accF[mi][ni][v] += wfv * tF[mi][ni][v];
                    accB[mi][ni][v] += wbv * tB[mi][ni][v];
                }
        }
        g0 = n0v; g1 = n1v;
    }

    // bf16 partials, [node][w]-major
#pragma unroll
    for (int mi = 0; mi < 2; ++mi)
#pragma unroll
        for (int v = 0; v < 4; ++v) {
            int m = wm * 32 + mi * 16 + lq * 4 + v;
#pragma unroll
            for (int ni = 0; ni < 2; ++ni) {
                int w = wn * 32 + ni * 16 + l16;
                partF[(size_t)gy * (NNODE * W128) + (B0 + m) * W128 + w]
                    = bf16t(accF[mi][ni][v]);
                partB[(size_t)gx * (NNODE * W128) + (A0 + m) * W128 + w]
                    = bf16t(accB[mi][ni][v]);
            }
        }
}

// ================= kernel B: reduce + own f32 args =================
// grid (16 n-tiles, 8 w-tiles), 256 thr. Tile 64 n x 16 w.
__global__ __launch_bounds__(256) void k_redB(const float* __restrict__ inputs,
                                              const float* __restrict__ a1w,
                                              const float* __restrict__ a2w,
                                              const float* __restrict__ opww,
                                              const short* __restrict__ partF,
                                              const short* __restrict__ partB,
                                              float* __restrict__ out) {
    __shared__ __align__(16) char smem[62720];
    float* lin = (float*)smem;                    // [128][65]
    float* sm1 = (float*)(smem + 33280);          // [16][128]
    float* sm2 = (float*)(smem + 41472);          // [16][128]
    float* a1s = (float*)(smem + 49664);          // [16][68]
    float* a2s = (float*)(smem + 54016);          // [16][68]
    float* chs = (float*)(smem + 58368);          // [64][17]
    int t = threadIdx.x;
    int n0 = blockIdx.x * 64;
    int w0 = blockIdx.y * 16;

    // stage inputs[:, n0..n0+64)
#pragma unroll
    for (int u = 0; u < 32; ++u) {
        int idx = t + u * 256;
        int j = idx >> 6, nn = idx & 63;
        lin[j * 65 + nn] = inputs[(size_t)j * NNODE + n0 + nn];
    }
    // column softmaxes for this block's 16 w (a1w and a2w)
    {
        int i = t & 15, c = t >> 4;
#pragma unroll
        for (int m2 = 0; m2 < 2; ++m2) {
            const float* src = m2 ? a2w : a1w;
            float* dst = m2 ? sm2 : sm1;
            int wcol = w0 + c;
            float v[8]; float mx = -1e30f;
#pragma unroll
            for (int k = 0; k < 8; ++k) { v[k] = src[(i * 8 + k) * W128 + wcol]; mx = fmaxf(mx, v[k]); }
#pragma unroll
            for (int off = 8; off; off >>= 1) mx = fmaxf(mx, __shfl_xor(mx, off));
            float s = 0.f;
#pragma unroll
            for (int k = 0; k < 8; ++k) { v[k] = expf(v[k] - mx); s += v[k]; }
#pragma unroll
            for (int off = 8; off; off >>= 1) s += __shfl_xor(s, off);
            float inv = 1.0f / s;
#pragma unroll
            for (int k = 0; k < 8; ++k) dst[c * W128 + i * 8 + k] = v[k] * inv;
        }
    }
    __syncthreads();
    // f32 a1/a2 for 16w x 64n
#pragma unroll
    for (int u = 0; u < 4; ++u) {
        int pair = t + u * 256;
        int nn = pair & 63, w_loc = pair >> 6;
        const float* s1 = sm1 + w_loc * W128;
        const float* s2 = sm2 + w_loc * W128;
        float a1 = 0.f, a2 = 0.f;
#pragma unroll 4
        for (int j = 0; j < W128; ++j) {
            float in = lin[j * 65 + nn];
            a1 = fmaf(s1[j], in, a1);
            a2 = fmaf(s2[j], in, a2);
        }
        a1s[w_loc * 68 + nn] = a1;
        a2s[w_loc * 68 + nn] = a2;
    }
    __syncthreads();
    // phase 1: reduce 32 partial slices (coalesced, lane-fast w)
    {
        int n_loc = t >> 2, wq = (t & 3) * 4;
        size_t base = (size_t)(n0 + n_loc) * W128 + w0 + wq;
        float c0 = 0.f, c1 = 0.f, c2 = 0.f, c3 = 0.f;
#pragma unroll
        for (int s = 0; s < 16; ++s) {
            short4v pf = *(const short4v*)&partF[(size_t)s * (NNODE * W128) + base];
            short4v pb = *(const short4v*)&partB[(size_t)s * (NNODE * W128) + base];
            c0 += bf16f(pf[0]) + bf16f(pb[0]);
            c1 += bf16f(pf[1]) + bf16f(pb[1]);
            c2 += bf16f(pf[2]) + bf16f(pb[2]);
            c3 += bf16f(pf[3]) + bf16f(pb[3]);
        }
        chs[n_loc * 17 + wq + 0] = c0;
        chs[n_loc * 17 + wq + 1] = c1;
        chs[n_loc * 17 + wq + 2] = c2;
        chs[n_loc * 17 + wq + 3] = c3;
    }
    __syncthreads();
    // phase 2: transposed epilogue (lane-fast n)
    {
        int w_loc = t >> 4, n4 = (t & 15) * 4;
        int w = w0 + w_loc;
        float v[5], mx = -1e30f;
#pragma unroll
        for (int k = 0; k < 5; ++k) { v[k] = opww[w * 5 + k]; mx = fmaxf(mx, v[k]); }
        float s5 = 0.f;
#pragma unroll
        for (int k = 0; k < 5; ++k) { v[k] = expf(v[k] - mx); s5 += v[k]; }
        float inv = 1.0f / s5;
        float ov[4];
#pragma unroll
        for (int j = 0; j < 4; ++j) {
            float ch = chs[(n4 + j) * 17 + w_loc];
            float a1 = a1s[w_loc * 68 + n4 + j];
            float a2 = a2s[w_loc * 68 + n4 + j];
            float p = a1 * a2;
            ov[j] = inv * (v[0] * a2 + v[1] * p + v[2] * (a1 + a2 - p)
                  + v[3] * (1.0f - expf(-ch)) + v[4] * (1.0f - a1));
        }
        float4 o = {ov[0], ov[1], ov[2], ov[3]};
        *(float4*)&out[(size_t)w * NNODE + n0 + n4] = o;
    }
}

extern "C" void kernel_launch(void* const* d_in, const int* in_sizes, int n_in,
                              void* d_out, int out_size, void* d_ws, size_t ws_size,
                              hipStream_t stream) {
    const float* inputs = (const float*)d_in[0];
    const float* db     = (const float*)d_in[1];
    const float* a1w    = (const float*)d_in[2];
    const float* a2w    = (const float*)d_in[3];
    const float* opww   = (const float*)d_in[4];
    const float* chw    = (const float*)d_in[5];
    float* out = (float*)d_out;
    short* partF = (short*)d_ws;
    short* partB = partF + (size_t)16 * NNODE * W128;

    hipLaunchKernelGGL(k_chainA, dim3(16, 16), dim3(512), 0, stream,
                       db, inputs, a2w, chw, partF, partB);
    hipLaunchKernelGGL(k_redB, dim3(16, 8), dim3(256), 0, stream,
                       inputs, a1w, a2w, opww, partF, partB, out);
}

// Round 18
// 33.988 us; speedup vs baseline: 5.9724x; 1.4375x over previous
//
#include <hip/hip_runtime.h>
#include <math.h>

#define W128  128
#define NNODE 1024
#define NREL  12
#define TS    72        // bf16 LDS tile stride (144B rows)

// ws layout (float offsets)
#define OFF_ARG1  0         // 128x1024 f32
#define OFF_ARG2  131072    // 128x1024 f32
#define OFF_ARG2B 262144    // 128x1024 bf16 (65536 floats)
#define OFF_PART  327680    // partF 16x1024x128 bf16, then partB same

typedef short bf16x8 __attribute__((ext_vector_type(8)));
typedef short short4v __attribute__((ext_vector_type(4)));
typedef float f32x4  __attribute__((ext_vector_type(4)));

__device__ __forceinline__ short bf16t(float x) {
    return (short)(__float_as_uint(x) >> 16);
}
__device__ __forceinline__ float bf16f(short s) {
    return __uint_as_float((unsigned)(unsigned short)s << 16);
}
__device__ __forceinline__ unsigned pk2(float lo, float hi) {
    return (__float_as_uint(hi) & 0xFFFF0000u) | (__float_as_uint(lo) >> 16);
}

// ---------------- args (+ in-block column softmaxes; replaces k_prep a1/a2) --
// grid 256: block = 32 n x 16 w tile, 512 threads.
__global__ __launch_bounds__(512) void k_args3(const float* __restrict__ inputs,
                                               const float* __restrict__ a1w,
                                               const float* __restrict__ a2w,
                                               float* __restrict__ ws,
                                               short* __restrict__ x2b) {
    __shared__ __align__(16) char smem[33280];
    float* lin = (float*)smem;               // [128][33]
    float* sm1 = (float*)(smem + 16896);     // [16][128]
    float* sm2 = sm1 + 16 * W128;            // [16][128]
    int t = threadIdx.x;
    int bid = blockIdx.x;
    int n0 = (bid & 31) * 32;
    int w0 = (bid >> 5) * 16;
    // stage inputs[128][32] once
#pragma unroll
    for (int u = 0; u < 8; ++u) {
        int idx = t + u * 512;
        int j = idx >> 5, nn = idx & 31;
        lin[j * 33 + nn] = inputs[j * NNODE + n0 + nn];
    }
    // 32 column softmaxes (16 w x {a1w,a2w}), 16 lanes per column
    {
        int c = t >> 4, i = t & 15;
        const float* src = (c < 16) ? a1w : a2w;
        float* dst = (c < 16) ? sm1 : sm2;
        int w_loc = c & 15;
        int wcol = w0 + w_loc;
        float v[8]; float mx = -1e30f;
#pragma unroll
        for (int k = 0; k < 8; ++k) {
            v[k] = src[(i * 8 + k) * W128 + wcol];
            mx = fmaxf(mx, v[k]);
        }
#pragma unroll
        for (int off = 8; off; off >>= 1) mx = fmaxf(mx, __shfl_xor(mx, off));
        float s = 0.f;
#pragma unroll
        for (int k = 0; k < 8; ++k) { v[k] = expf(v[k] - mx); s += v[k]; }
#pragma unroll
        for (int off = 8; off; off >>= 1) s += __shfl_xor(s, off);
        float inv = 1.0f / s;
#pragma unroll
        for (int k = 0; k < 8; ++k) dst[w_loc * W128 + i * 8 + k] = v[k] * inv;
    }
    __syncthreads();
    // each thread: one (n, w) pair
    int nn = t & 31, w_loc = t >> 5;
    int n = n0 + nn, w = w0 + w_loc;
    const float* s1 = sm1 + w_loc * W128;
    const float* s2 = sm2 + w_loc * W128;
    float a1 = 0.f, a2 = 0.f;
#pragma unroll 4
    for (int j = 0; j < W128; ++j) {
        float in = lin[j * 33 + nn];
        a1 = fmaf(s1[j], in, a1);
        a2 = fmaf(s2[j], in, a2);
    }
    ws[OFF_ARG1 + w * NNODE + n] = a1;
    ws[OFF_ARG2 + w * NNODE + n] = a2;
    x2b[w * NNODE + n] = bf16t(a2);
}

// ---------------- chain (+ in-block wf/wb softmax) ----
// grid (16,16), 512 threads. Dual-use 64x64 db tile, bf16 packed at staging.
__global__ __launch_bounds__(512) void k_chain4(const float* __restrict__ db,
                                                const float* __restrict__ chw,
                                                const short* __restrict__ x2b,
                                                short* __restrict__ partF,
                                                short* __restrict__ partB) {
    __shared__ __align__(16) short Tf[64 * TS];  // T[a][b]
    __shared__ __align__(16) short Tt[64 * TS];  // T^T[c][a]
    __shared__ float wfs[W128 * NREL];
    __shared__ float wbs[W128 * NREL];

    int tid = threadIdx.x;
    int B0  = blockIdx.x * 64;   // fwd out-node range / bwd contraction range
    int A0  = blockIdx.y * 64;   // bwd out-node range / fwd contraction range

    // issue first tile's global loads ASAP (overlap with softmax below)
    int a0 = 2 * (tid >> 4), c0 = 4 * (tid & 15);
    const float* gbase = db + (size_t)(A0 + a0) * NNODE + B0 + c0;
    const size_t rstep = (size_t)NNODE * NNODE;
    float4 g0 = *(const float4*)(gbase);
    float4 g1 = *(const float4*)(gbase + NNODE);

    // in-block chain-weight softmax
    if (tid < 128) {
        float u[24]; float mx = -1e30f;
        for (int k = 0; k < 24; ++k) { u[k] = chw[tid * 24 + k]; mx = fmaxf(mx, u[k]); }
        float s = 0.f;
        for (int k = 0; k < 24; ++k) { u[k] = expf(u[k] - mx); s += u[k]; }
        float inv = 1.0f / s;
        for (int k = 0; k < 12; ++k) wfs[tid * NREL + k] = u[k] * inv;
        for (int k = 0; k < 12; ++k) wbs[tid * NREL + k] = u[12 + k] * inv;
    }

    int l   = tid & 63, wid = tid >> 6;
    int wm  = wid >> 2;          // 0..1 : node-half (m)
    int wn  = wid & 3;           // 0..3 : w-quarter (n)
    int l16 = l & 15, lq = l >> 4;

    // loop-invariant B-frags from x2b
    bf16x8 bfF[2][2], bfB[2][2];
#pragma unroll
    for (int ni = 0; ni < 2; ++ni)
#pragma unroll
        for (int ks = 0; ks < 2; ++ks) {
            int w = wn * 32 + ni * 16 + l16;
            bfF[ni][ks] = *(const bf16x8*)&x2b[w * NNODE + A0 + ks * 32 + lq * 8];
            bfB[ni][ks] = *(const bf16x8*)&x2b[w * NNODE + B0 + ks * 32 + lq * 8];
        }

    f32x4 accF[2][2], accB[2][2];
#pragma unroll
    for (int mi = 0; mi < 2; ++mi)
#pragma unroll
        for (int ni = 0; ni < 2; ++ni) {
            accF[mi][ni] = (f32x4){0.f, 0.f, 0.f, 0.f};
            accB[mi][ni] = (f32x4){0.f, 0.f, 0.f, 0.f};
        }

#pragma unroll 2
    for (int r = 0; r < NREL; ++r) {
        // stage packed bf16 tiles (pack once; consumers read b128 only)
        uint2 p0 = {pk2(g0.x, g0.y), pk2(g0.z, g0.w)};
        uint2 p1 = {pk2(g1.x, g1.y), pk2(g1.z, g1.w)};
        *(uint2*)&Tf[a0 * TS + c0]       = p0;
        *(uint2*)&Tf[(a0 + 1) * TS + c0] = p1;
        *(unsigned*)&Tt[(c0 + 0) * TS + a0] = pk2(g0.x, g1.x);
        *(unsigned*)&Tt[(c0 + 1) * TS + a0] = pk2(g0.y, g1.y);
        *(unsigned*)&Tt[(c0 + 2) * TS + a0] = pk2(g0.z, g1.z);
        *(unsigned*)&Tt[(c0 + 3) * TS + a0] = pk2(g0.w, g1.w);
        __syncthreads();

        float4 n0v = g0, n1v = g1;
        if (r + 1 < NREL) {
            const float* g = gbase + (size_t)(r + 1) * rstep;
            n0v = *(const float4*)(g);
            n1v = *(const float4*)(g + NNODE);
        }

        f32x4 tF[2][2], tB[2][2];
#pragma unroll
        for (int mi = 0; mi < 2; ++mi)
#pragma unroll
            for (int ni = 0; ni < 2; ++ni) {
                tF[mi][ni] = (f32x4){0.f, 0.f, 0.f, 0.f};
                tB[mi][ni] = (f32x4){0.f, 0.f, 0.f, 0.f};
            }

#pragma unroll
        for (int ks = 0; ks < 2; ++ks) {
            bf16x8 AF[2], AB[2];
#pragma unroll
            for (int mi = 0; mi < 2; ++mi) {
                int row = wm * 32 + mi * 16 + l16;
                int off = ks * 32 + lq * 8;
                AF[mi] = *(const bf16x8*)&Tt[row * TS + off];
                AB[mi] = *(const bf16x8*)&Tf[row * TS + off];
            }
#pragma unroll
            for (int mi = 0; mi < 2; ++mi)
#pragma unroll
                for (int ni = 0; ni < 2; ++ni) {
                    tF[mi][ni] = __builtin_amdgcn_mfma_f32_16x16x32_bf16(
                        AF[mi], bfF[ni][ks], tF[mi][ni], 0, 0, 0);
                    tB[mi][ni] = __builtin_amdgcn_mfma_f32_16x16x32_bf16(
                        AB[mi], bfB[ni][ks], tB[mi][ni], 0, 0, 0);
                }
        }
        __syncthreads();

        // fold per-(w,r) chain weights (w = lane column)
#pragma unroll
        for (int ni = 0; ni < 2; ++ni) {
            int w = wn * 32 + ni * 16 + l16;
            float wfv = wfs[w * NREL + r];
            float wbv = wbs[w * NREL + r];
#pragma unroll
            for (int mi = 0; mi < 2; ++mi)
#pragma unroll
                for (int v = 0; v < 4; ++v) {
                    accF[mi][ni][v] += wfv * tF[mi][ni][v];
                    accB[mi][ni][v] += wbv * tB[mi][ni][v];
                }
        }
        g0 = n0v; g1 = n1v;
    }

    // bf16 partials, [node][w]-major
#pragma unroll
    for (int mi = 0; mi < 2; ++mi)
#pragma unroll
        for (int v = 0; v < 4; ++v) {
            int m = wm * 32 + mi * 16 + lq * 4 + v;
#pragma unroll
            for (int ni = 0; ni < 2; ++ni) {
                int w = wn * 32 + ni * 16 + l16;
                partF[(size_t)blockIdx.y * (NNODE * W128) + (B0 + m) * W128 + w]
                    = bf16t(accF[mi][ni][v]);
                partB[(size_t)blockIdx.x * (NNODE * W128) + (A0 + m) * W128 + w]
                    = bf16t(accB[mi][ni][v]);
            }
        }
}

// ---------------- reduce (+ per-thread opw softmax) ----
// grid (16 n-tiles x 8 w-tiles), 256 thr. Block tile: 64 n x 16 w.
__global__ __launch_bounds__(256) void k_reduce4(const float* __restrict__ ws,
                                                 const float* __restrict__ opww,
                                                 const short* __restrict__ partF,
                                                 const short* __restrict__ partB,
                                                 float* __restrict__ out) {
    __shared__ float chs[64 * 17];
    int t = threadIdx.x;
    int n0 = blockIdx.x * 64;
    int w0 = blockIdx.y * 16;
    // phase 1: reduce slices; thread owns (n_loc, 4 w's)
    {
        int n_loc = t >> 2;
        int wq = (t & 3) * 4;
        size_t base = (size_t)(n0 + n_loc) * W128 + w0 + wq;
        float c0 = 0.f, c1 = 0.f, c2 = 0.f, c3 = 0.f;
#pragma unroll
        for (int s = 0; s < 16; ++s) {
            short4v pf = *(const short4v*)&partF[(size_t)s * (NNODE * W128) + base];
            short4v pb = *(const short4v*)&partB[(size_t)s * (NNODE * W128) + base];
            c0 += bf16f(pf[0]) + bf16f(pb[0]);
            c1 += bf16f(pf[1]) + bf16f(pb[1]);
            c2 += bf16f(pf[2]) + bf16f(pb[2]);
            c3 += bf16f(pf[3]) + bf16f(pb[3]);
        }
        chs[n_loc * 17 + wq + 0] = c0;
        chs[n_loc * 17 + wq + 1] = c1;
        chs[n_loc * 17 + wq + 2] = c2;
        chs[n_loc * 17 + wq + 3] = c3;
    }
    __syncthreads();
    // phase 2: thread owns (w_loc, 4 n's); all global IO coalesced
    {
        int w_loc = t >> 4;          // 0..15
        int n4 = (t & 15) * 4;       // 0..60
        int w = w0 + w_loc;
        float ch[4];
#pragma unroll
        for (int j = 0; j < 4; ++j) ch[j] = chs[(n4 + j) * 17 + w_loc];
        // per-thread op-weight softmax
        float v[5], mx = -1e30f;
#pragma unroll
        for (int k = 0; k < 5; ++k) { v[k] = opww[w * 5 + k]; mx = fmaxf(mx, v[k]); }
        float s5 = 0.f;
#pragma unroll
        for (int k = 0; k < 5; ++k) { v[k] = expf(v[k] - mx); s5 += v[k]; }
        float inv = 1.0f / s5;
        float4 a1 = *(const float4*)&ws[OFF_ARG1 + w * NNODE + n0 + n4];
        float4 a2 = *(const float4*)&ws[OFF_ARG2 + w * NNODE + n0 + n4];
        float a1v[4] = {a1.x, a1.y, a1.z, a1.w};
        float a2v[4] = {a2.x, a2.y, a2.z, a2.w};
        float ov[4];
#pragma unroll
        for (int j = 0; j < 4; ++j) {
            float p = a1v[j] * a2v[j];
            ov[j] = inv * (v[0] * a2v[j] + v[1] * p + v[2] * (a1v[j] + a2v[j] - p)
                  + v[3] * (1.0f - expf(-ch[j])) + v[4] * (1.0f - a1v[j]));
        }
        float4 o = {ov[0], ov[1], ov[2], ov[3]};
        *(float4*)&out[w * NNODE + n0 + n4] = o;
    }
}

extern "C" void kernel_launch(void* const* d_in, const int* in_sizes, int n_in,
                              void* d_out, int out_size, void* d_ws, size_t ws_size,
                              hipStream_t stream) {
    const float* inputs = (const float*)d_in[0];
    const float* db     = (const float*)d_in[1];
    const float* a1w    = (const float*)d_in[2];
    const float* a2w    = (const float*)d_in[3];
    const float* opww   = (const float*)d_in[4];
    const float* chw    = (const float*)d_in[5];
    float* ws  = (float*)d_ws;
    float* out = (float*)d_out;
    short* x2b   = (short*)(ws + OFF_ARG2B);
    short* partF = (short*)(ws + OFF_PART);
    short* partB = partF + (size_t)16 * NNODE * W128;

    hipLaunchKernelGGL(k_args3, dim3(256), dim3(512), 0, stream,
                       inputs, a1w, a2w, ws, x2b);
    hipLaunchKernelGGL(k_chain4, dim3(16, 16), dim3(512), 0, stream,
                       db, chw, x2b, partF, partB);
    hipLaunchKernelGGL(k_reduce4, dim3(16, 8), dim3(256), 0, stream,
                       ws, opww, partF, partB, out);
}